// Round 3
// baseline (133.837 us; speedup 1.0000x reference)
//
#include <hip/hip_runtime.h>
#include <stdint.h>

// ODE: y' = tanh(y@W1+b1)@W2+b2, dopri5 fixed-step (dt=0.05, 20 steps, out every 4).
// Split-H wave-pair formulation: each 16-row batch tile is owned by TWO waves;
// wave w handles hidden rows [64w,64w+64). Layer outputs stay in C-layout
// registers (batch = MFMA N-dim); per-lane cvt_pk repack feeds the next MFMA.
// The pair exchanges partial k (16 f32/lane) via double-buffered coalesced LDS.
// 2048 waves = 2 waves/SIMD -> cross-wave MFMA/VALU overlap.

typedef __attribute__((ext_vector_type(8))) short short8;   // 8 bf16 (4 VGPRs)
typedef __attribute__((ext_vector_type(4))) float f32x4;

union U8 { uint32_t u[4]; short8 s; };

__device__ __forceinline__ uint32_t cvt_pk_bf16(float a, float b){
    uint32_t r;
    asm("v_cvt_pk_bf16_f32 %0, %1, %2" : "=v"(r) : "v"(a), "v"(b));
    return r;
}

__device__ __forceinline__ float fast_tanh(float x){
    // tanh(x) = 1 - 2/(1+e^{2x});  v_exp_f32 computes 2^x
    float e = __builtin_amdgcn_exp2f(x * 2.885390081777927f);   // 2*log2(e)
    float r = __builtin_amdgcn_rcpf(1.0f + e);
    return __builtin_fmaf(-2.0f, r, 1.0f);
}

// One f-eval. z, kout: C-layout f32x4[4]; z[dt][q] = state[batch=m][feat dt*16+4g+q].
// Wave computes its H-half, exchanges partial k with partner via xch (per-pair,
// per-feval-parity LDS region), returns full k (incl. b2).
__device__ __forceinline__ void odef(
    const f32x4 (&z)[4], f32x4 (&kout)[4],
    const short8 (&a1)[4][2], const short8 (&a2)[4][2],
    const f32x4 (&b1v)[4], const f32x4 (&b2v)[4],
    float* __restrict__ xch, int w, int lane)
{
    // repack full z (C-layout) -> B-fragments, pure per-lane
    short8 zb[2];
    #pragma unroll
    for (int kc=0; kc<2; ++kc){
        U8 u;
        u.u[0] = cvt_pk_bf16(z[2*kc  ][0], z[2*kc  ][1]);
        u.u[1] = cvt_pk_bf16(z[2*kc  ][2], z[2*kc  ][3]);
        u.u[2] = cvt_pk_bf16(z[2*kc+1][0], z[2*kc+1][1]);
        u.u[3] = cvt_pk_bf16(z[2*kc+1][2], z[2*kc+1][3]);
        zb[kc] = u.s;
    }

    // layer 1 (this wave's H-half): h = tanh(W1^T z^T + b1)
    f32x4 hreg[4];
    #pragma unroll
    for (int nt=0; nt<4; ++nt){
        f32x4 acc = b1v[nt];
        acc = __builtin_amdgcn_mfma_f32_16x16x32_bf16(a1[nt][0], zb[0], acc, 0,0,0);
        acc = __builtin_amdgcn_mfma_f32_16x16x32_bf16(a1[nt][1], zb[1], acc, 0,0,0);
        #pragma unroll
        for (int q=0; q<4; ++q) hreg[nt][q] = fast_tanh(acc[q]);
    }

    // repack h -> B-fragments
    short8 hb[2];
    #pragma unroll
    for (int kc=0; kc<2; ++kc){
        U8 u;
        u.u[0] = cvt_pk_bf16(hreg[2*kc  ][0], hreg[2*kc  ][1]);
        u.u[1] = cvt_pk_bf16(hreg[2*kc  ][2], hreg[2*kc  ][3]);
        u.u[2] = cvt_pk_bf16(hreg[2*kc+1][0], hreg[2*kc+1][1]);
        u.u[3] = cvt_pk_bf16(hreg[2*kc+1][2], hreg[2*kc+1][3]);
        hb[kc] = u.s;
    }

    // layer 2 partial: kp = W2^T[:, H-half] h_half
    f32x4 kp[4];
    #pragma unroll
    for (int dt=0; dt<4; ++dt){
        f32x4 acc = {0.f,0.f,0.f,0.f};
        acc = __builtin_amdgcn_mfma_f32_16x16x32_bf16(a2[dt][0], hb[0], acc, 0,0,0);
        acc = __builtin_amdgcn_mfma_f32_16x16x32_bf16(a2[dt][1], hb[1], acc, 0,0,0);
        kp[dt] = acc;
    }

    // exchange partials with partner wave (coalesced: lane-consecutive 16B)
    #pragma unroll
    for (int j=0; j<4; ++j)
        *(f32x4*)(xch + (j*2 + w)*256 + lane*4) = kp[j];
    __syncthreads();
    #pragma unroll
    for (int j=0; j<4; ++j){
        const f32x4 other = *(const f32x4*)(xch + (j*2 + (w^1))*256 + lane*4);
        kout[j] = kp[j] + other + b2v[j];
    }
}

__global__ __launch_bounds__(256, 2)
void ode_dopri5_kernel(const float* __restrict__ init_pos,
                       const float* __restrict__ W1, const float* __restrict__ b1,
                       const float* __restrict__ W2, const float* __restrict__ b2,
                       float* __restrict__ out)
{
    // 32 KB: weight staging during init, then (pair,buf) k-exchange regions.
    __shared__ __align__(16) float lds[8192];

    const int tid  = threadIdx.x;
    const int wavei = tid >> 6;
    const int lane = tid & 63;
    const int pair = wavei >> 1;    // 2 pairs per block
    const int w    = wavei & 1;     // H-half owner
    const int m = lane & 15;        // batch col
    const int g = lane >> 4;

    // ---- stage W1 (f32, coalesced); build this wave's W1^T A-fragments ----
    {
        const f32x4* s = (const f32x4*)W1;
        f32x4* d = (f32x4*)lds;
        #pragma unroll
        for (int i=0; i<8; ++i) d[tid + 256*i] = s[tid + 256*i];
    }
    __syncthreads();

    short8 a1[4][2];   // rows n = w*64 + nt*16 + m, k = feature
    #pragma unroll
    for (int nt=0; nt<4; ++nt)
        #pragma unroll
        for (int kc=0; kc<2; ++kc){
            U8 u;
            #pragma unroll
            for (int j=0; j<4; ++j){
                int kb = kc*32 + ((j<2) ? (4*g + 2*j) : (16 + 4*g + 2*(j-2)));
                u.u[j] = cvt_pk_bf16(lds[(kb  )*128 + w*64 + nt*16 + m],
                                     lds[(kb+1)*128 + w*64 + nt*16 + m]);
            }
            a1[nt][kc] = u.s;
        }
    __syncthreads();

    // ---- stage W2; build this wave's W2^T A-fragments (k = hidden half) ----
    {
        const f32x4* s = (const f32x4*)W2;
        f32x4* d = (f32x4*)lds;
        #pragma unroll
        for (int i=0; i<8; ++i) d[tid + 256*i] = s[tid + 256*i];
    }
    __syncthreads();

    short8 a2[4][2];   // rows d = dt*16 + m, k = w*64 + kc*32 + phi(g,j)
    #pragma unroll
    for (int dt=0; dt<4; ++dt)
        #pragma unroll
        for (int kc=0; kc<2; ++kc){
            U8 u;
            #pragma unroll
            for (int j=0; j<4; ++j){
                int nb = w*64 + kc*32 + ((j<2) ? (4*g + 2*j) : (16 + 4*g + 2*(j-2)));
                u.u[j] = cvt_pk_bf16(lds[(nb  )*64 + dt*16 + m],
                                     lds[(nb+1)*64 + dt*16 + m]);
            }
            a2[dt][kc] = u.s;
        }
    __syncthreads();   // lds now becomes the exchange buffer

    // ---- biases: b1 half per wave, b2 full (added once, post-exchange) ----
    f32x4 b1v[4], b2v[4];
    #pragma unroll
    for (int nt=0; nt<4; ++nt)
        b1v[nt] = *(const f32x4*)(b1 + (w*4 + nt)*16 + 4*g);
    #pragma unroll
    for (int dt=0; dt<4; ++dt)
        b2v[dt] = *(const f32x4*)(b2 + dt*16 + 4*g);

    // ---- load y in C-layout (both waves of pair hold the same 16 rows) ----
    const int row0 = (blockIdx.x*2 + pair) * 16;
    f32x4 y[4];
    #pragma unroll
    for (int dt=0; dt<4; ++dt)
        y[dt] = *(const f32x4*)(init_pos + (size_t)(row0 + m)*64 + dt*16 + 4*g);

    // exchange regions: (pair, feval-parity) -> 2048 f32 each
    float* xchA = lds + (pair*2 + 0)*2048;
    float* xchB = lds + (pair*2 + 1)*2048;

    // Dopri5 coefficients
    const float dt_h = 0.05f;
    const float A21 = 0.2f;
    const float A31 = 0.075f,             A32 = 0.225f;
    const float A41 = 44.f/45.f,  A42 = -56.f/15.f,    A43 = 32.f/9.f;
    const float A51 = 19372.f/6561.f, A52 = -25360.f/2187.f, A53 = 64448.f/6561.f, A54 = -212.f/729.f;
    const float A61 = 9017.f/3168.f,  A62 = -355.f/33.f,     A63 = 46732.f/5247.f, A64 = 49.f/176.f, A65 = -5103.f/18656.f;
    const float B1  = 35.f/384.f, B3 = 500.f/1113.f, B4 = 125.f/192.f, B5 = -2187.f/6784.f, B6 = 11.f/84.f;

    f32x4 k1[4], k2[4], k3[4], k4[4], k5[4], k6[4], z[4];

    for (int step=0; step<20; ++step){
        odef(y, k1, a1, a2, b1v, b2v, xchA, w, lane);
        #pragma unroll
        for (int i=0;i<4;++i) z[i] = y[i] + dt_h*(A21*k1[i]);
        odef(z, k2, a1, a2, b1v, b2v, xchB, w, lane);
        #pragma unroll
        for (int i=0;i<4;++i) z[i] = y[i] + dt_h*(A31*k1[i] + A32*k2[i]);
        odef(z, k3, a1, a2, b1v, b2v, xchA, w, lane);
        #pragma unroll
        for (int i=0;i<4;++i) z[i] = y[i] + dt_h*(A41*k1[i] + A42*k2[i] + A43*k3[i]);
        odef(z, k4, a1, a2, b1v, b2v, xchB, w, lane);
        #pragma unroll
        for (int i=0;i<4;++i) z[i] = y[i] + dt_h*(A51*k1[i] + A52*k2[i] + A53*k3[i] + A54*k4[i]);
        odef(z, k5, a1, a2, b1v, b2v, xchA, w, lane);
        #pragma unroll
        for (int i=0;i<4;++i) z[i] = y[i] + dt_h*(A61*k1[i] + A62*k2[i] + A63*k3[i] + A64*k4[i] + A65*k5[i]);
        odef(z, k6, a1, a2, b1v, b2v, xchB, w, lane);
        #pragma unroll
        for (int i=0;i<4;++i) y[i] = y[i] + dt_h*(B1*k1[i] + B3*k3[i] + B4*k4[i] + B5*k5[i] + B6*k6[i]);

        if ((step & 3) == 3){
            const int e = step >> 2;
            float* o = out + (size_t)e*16384*64 + (size_t)(row0 + m)*64;
            // waves of the pair hold identical y; split the store by dt
            #pragma unroll
            for (int d2=0; d2<2; ++d2){
                const int dt = 2*w + d2;
                *(f32x4*)(o + dt*16 + 4*g) = y[dt];
            }
        }
    }
}

extern "C" void kernel_launch(void* const* d_in, const int* in_sizes, int n_in,
                              void* d_out, int out_size, void* d_ws, size_t ws_size,
                              hipStream_t stream)
{
    (void)in_sizes; (void)n_in; (void)out_size; (void)d_ws; (void)ws_size;
    const float* init_pos = (const float*)d_in[0];
    const float* W1 = (const float*)d_in[1];
    const float* b1 = (const float*)d_in[2];
    const float* W2 = (const float*)d_in[3];
    const float* b2 = (const float*)d_in[4];
    float* out = (float*)d_out;

    hipLaunchKernelGGL(ode_dopri5_kernel, dim3(512), dim3(256), 0, stream,
                       init_pos, W1, b1, W2, b2, out);
}